// Round 2
// baseline (144.070 us; speedup 1.0000x reference)
//
#include <hip/hip_runtime.h>

typedef __bf16 bf16;
typedef __attribute__((ext_vector_type(8))) __bf16 bf16x8;
typedef __attribute__((ext_vector_type(4))) __bf16 bf16x4;
typedef __attribute__((ext_vector_type(4))) float floatx4;

#define MFMA16(a, b, c) __builtin_amdgcn_mfma_f32_16x16x32_bf16((a), (b), (c), 0, 0, 0)

// ---------------------------------------------------------------------------
// Kernel 0: W [1024][64] fp32 x3 -> wTf, FRAGMENT-MAJOR bf16:
//   wTf[(((mt*32 + kc)*4 + q)*16 + l)*8 + j] = A[m = mt*16+l][k = kc*32+q*8+j]
//   where A[m][c] = W_{m/64}[c][m%64].
// ---------------------------------------------------------------------------
__global__ void prep_w(const float* __restrict__ Wq, const float* __restrict__ Wk,
                       const float* __restrict__ Wv, bf16* __restrict__ wTf) {
    int tid = blockIdx.x * 256 + threadIdx.x;   // [0, 196608)
    int j = tid & 7;
    int l = (tid >> 3) & 15;
    int q = (tid >> 7) & 3;
    int kc = (tid >> 9) & 31;
    int mt = tid >> 14;                          // 0..11
    int mat = mt >> 2;
    int h = ((mt & 3) << 4) + l;
    int c = kc * 32 + q * 8 + j;
    const float* W = (mat == 0) ? Wq : (mat == 1) ? Wk : Wv;
    wTf[tid] = (bf16)W[c * 64 + h];
}

// ---------------------------------------------------------------------------
// Kernel 1: QKV projection, K-PIPELINED staging. Block = 256 thr (4 waves) =
// ONE 32-row t-tile (512 blocks). x is staged in 16 chunks of 64 columns
// (32 B/thread/chunk), software-pipelined against the MFMA K-loop:
//   iter c: issue loads chunk c+3 -> regs | compute chunk c (kc=2c,2c+1,
//   12 MFMAs) | write chunk c+1 regs->LDS | barrier.
// HBM x-read (64 MB grid-wide) now overlaps the wTf L2 stream + MFMA instead
// of serializing ahead of it. LDS layout identical to before: 64 KB
// [32 rows][2048 B], XOR-swizzled (byte ^= (row&7)<<4 on write AND read).
// ---------------------------------------------------------------------------
__global__ __launch_bounds__(256, 2) void proj_qkv(const float* __restrict__ x,
                                                   const bf16* __restrict__ wTf,
                                                   bf16* __restrict__ q,
                                                   bf16* __restrict__ k,
                                                   bf16* __restrict__ vT) {
    __shared__ __align__(16) char xsb[32 * 2048];   // 64 KB exact

    const int tid = threadIdx.x;
    const int lane = tid & 63;
    const int w = tid >> 6;          // wave 0..3 = m-group
    const int l15 = lane & 15;
    const int quad = lane >> 4;
    const int T0 = blockIdx.x * 32;

    // stage mapping: thread -> (row = tid>>3, colgroup = tid&7); per chunk c
    // loads 8 consecutive fp32 (32 B) of row at cols c*64 + cg*8, stores one
    // swizzled bf16x8. Per wave: 8 rows x 256 B contiguous segments.
    const int srow = tid >> 3;
    const int scg = tid & 7;
    const float* sg = x + (size_t)(T0 + srow) * 1024 + scg * 8;
    char* sld = xsb + srow * 2048;
    const int sws = (srow & 7) << 4;

#define STC(c, f0, f1)                                                          \
    {                                                                            \
        bf16x8 pk;                                                               \
        pk[0] = (bf16)(f0)[0]; pk[1] = (bf16)(f0)[1];                            \
        pk[2] = (bf16)(f0)[2]; pk[3] = (bf16)(f0)[3];                            \
        pk[4] = (bf16)(f1)[0]; pk[5] = (bf16)(f1)[1];                            \
        pk[6] = (bf16)(f1)[2]; pk[7] = (bf16)(f1)[3];                            \
        *(bf16x8*)(sld + (((c) * 128 + scg * 16) ^ sws)) = pk;                   \
    }

    // prologue: chunks 0,1,2 in flight; store chunk 0; barrier.
    floatx4 A0 = *(const floatx4*)(sg);
    floatx4 A1 = *(const floatx4*)(sg + 4);
    floatx4 B0 = *(const floatx4*)(sg + 64);
    floatx4 B1 = *(const floatx4*)(sg + 68);
    floatx4 C0 = *(const floatx4*)(sg + 128);
    floatx4 C1 = *(const floatx4*)(sg + 132);
    STC(0, A0, A1);
    __syncthreads();

    // ---- compute set-up: depth-2 A prefetch; 6 MFMAs per A-fragment triple.
    floatx4 acc[6] = {};     // [i=mtile 0..2][tt=0..1] flattened i*2+tt
    const bf16* aw0 = wTf + (size_t)(w * 3 + 0) * 16384 + lane * 8;
    const bf16* aw1 = wTf + (size_t)(w * 3 + 1) * 16384 + lane * 8;
    const bf16* aw2 = wTf + (size_t)(w * 3 + 2) * 16384 + lane * 8;
    const char* xr = xsb + l15 * 2048;           // t-row l15 (tt=0); +32768 for tt=1
    const int sx = (l15 & 7) << 4;               // same for row l15+16
    const int q16 = quad * 16;

    bf16x8 a0c = *(const bf16x8*)(aw0);
    bf16x8 a1c = *(const bf16x8*)(aw1);
    bf16x8 a2c = *(const bf16x8*)(aw2);
    bf16x8 a0n = *(const bf16x8*)(aw0 + 512);
    bf16x8 a1n = *(const bf16x8*)(aw1 + 512);
    bf16x8 a2n = *(const bf16x8*)(aw2 + 512);

    #pragma unroll
    for (int c = 0; c < 16; c++) {
        // issue chunk c+3 global loads early (~2.5 chunks of slack)
        floatx4 N0 = {}, N1 = {};
        if (c < 13) {
            N0 = *(const floatx4*)(sg + (c + 3) * 64);
            N1 = *(const floatx4*)(sg + (c + 3) * 64 + 4);
        }
        #pragma unroll
        for (int u = 0; u < 2; u++) {
            const int kc = 2 * c + u;
            // A-prefetch kc+2 (2-iteration slack; reads 4KB slack past end)
            bf16x8 p0 = *(const bf16x8*)(aw0 + (kc + 2) * 512);
            bf16x8 p1 = *(const bf16x8*)(aw1 + (kc + 2) * 512);
            bf16x8 p2 = *(const bf16x8*)(aw2 + (kc + 2) * 512);
            const int o = (kc * 64 + q16) ^ sx;
            bf16x8 b0 = *(const bf16x8*)(xr + o);
            bf16x8 b1 = *(const bf16x8*)(xr + 32768 + o);
            acc[0] = MFMA16(a0c, b0, acc[0]);
            acc[1] = MFMA16(a0c, b1, acc[1]);
            acc[2] = MFMA16(a1c, b0, acc[2]);
            acc[3] = MFMA16(a1c, b1, acc[3]);
            acc[4] = MFMA16(a2c, b0, acc[4]);
            acc[5] = MFMA16(a2c, b1, acc[5]);
            a0c = a0n; a1c = a1n; a2c = a2n;
            a0n = p0;  a1n = p1;  a2n = p2;
        }
        if (c < 15) STC(c + 1, B0, B1);
        __syncthreads();
        B0 = C0; B1 = C1; C0 = N0; C1 = N1;
    }
#undef STC

    // Epilogue. C-layout: (i,r) -> out-row m = (w*3+i)*16 + quad*4 + r
    // (mat = m/64, h = m%64), out-col t = T0 + tt*16 + l15.
    // q gets (1/8)*log2(e) folded (flash softmax runs in base-2).
    #pragma unroll
    for (int i = 0; i < 3; i++) {
        int mtile = w * 3 + i;
        int mat = mtile >> 2;                          // wave-uniform
        int hbase = ((mtile & 3) << 4) + (quad << 2);
        float sc = (mat == 0) ? 0.18033688011112042f : 1.0f;
        #pragma unroll
        for (int tt = 0; tt < 2; tt++) {
            const int t = T0 + tt * 16 + l15;
            floatx4 av = acc[i * 2 + tt];
            bf16x4 pk;
            pk[0] = (bf16)(av[0] * sc);
            pk[1] = (bf16)(av[1] * sc);
            pk[2] = (bf16)(av[2] * sc);
            pk[3] = (bf16)(av[3] * sc);
            if (mat == 0) {
                *(bf16x4*)(q + (size_t)t * 64 + hbase) = pk;
            } else if (mat == 1) {
                *(bf16x4*)(k + (size_t)t * 64 + hbase) = pk;
            } else {
                int bidx = t >> 11, tmod = t & 2047;
                #pragma unroll
                for (int r = 0; r < 4; r++)
                    vT[(size_t)(bidx * 64 + hbase + r) * 2048 + tmod] = pk[r];
            }
        }
    }
}

// ---------------------------------------------------------------------------
// Kernel 2: causal flash attention, S^T formulation, uniform two-tile blocks.
// Softmax runs in BASE-2 (log2e folded into q) -> every exp is one v_exp_f32.
// T13 defer-max: when __all(mx - m <= 8) keep old running max and skip the
// O-rescale pass. T5 setprio around MFMA clusters. Max reduction shaped as
// fmax(fmax(a,b),c) triples so clang emits v_max3_f32 (8 ops vs 15).
// ---------------------------------------------------------------------------
#define KP2 72
#define OH 68

__global__ __launch_bounds__(512, 4) void flash(const bf16* __restrict__ q,
                                                const bf16* __restrict__ k,
                                                const bf16* __restrict__ vT,
                                                float* __restrict__ out) {
    __shared__ char smem[8 * 16 * OH * 4];   // union: ps (loop) / Os (merge)
    __shared__ float Ms[8][16], Ls[8][16];
    bf16* psall = (bf16*)smem;
    float* Os = (float*)smem;                // [w][q=16][OH]

    const int b = blockIdx.x & 7;            // batch -> XCD affinity
    const int p = blockIdx.x >> 3;           // 0..63
    const int t0A = p * 16;
    const int t0B = (127 - p) * 16;
    const int nttA = (p >> 2) + 1;
    const int nttB = ((127 - p) >> 2) + 1;
    const int L = nttA + nttB;               // 32..34 for all blocks

    const int tid = threadIdx.x;
    const int w = tid >> 6;
    const int lane = tid & 63;
    const int l15 = lane & 15;
    const int quad = lane >> 4;

    const int s0 = (L * w) >> 3;
    const int s1 = (L * (w + 1)) >> 3;

    const bf16* kbase = k + (size_t)(b * 2048 + l15) * 64 + quad * 8;   // + jt*4096 + mt*1024 + c*32
    const bf16* vbase = vT + (size_t)(b * 64 + l15) * 2048 + quad * 8;  // + mt*32768 + jt*64 + kc*32
    bf16* psw = psall + w * 16 * KP2;

    // Q B-frags: lane n=l15 -> q-row, k = h = quad*8+j (+32)
    const bf16* qpA = q + (size_t)(b * 2048 + t0A + l15) * 64 + quad * 8;
    const bf16* qpB = q + (size_t)(b * 2048 + t0B + l15) * 64 + quad * 8;

    floatx4 oA[4] = {}, oB[4] = {};
    float miA = -1e30f, liA = 0.f, miB = -1e30f, liB = 0.f;

#define KV_STEP(jtv, isdiag, t0v, qf0v, qf1v, mi_, li_, o_)                          \
    {                                                                                 \
        const bf16* kp = kbase + (size_t)(jtv) * 4096;                                \
        floatx4 stt[4];                                                               \
        __builtin_amdgcn_s_setprio(1);                                                \
        _Pragma("unroll") for (int mt = 0; mt < 4; mt++) {                            \
            floatx4 z = {};                                                           \
            bf16x8 ka0 = *(const bf16x8*)(kp + mt * 1024);                            \
            bf16x8 ka1 = *(const bf16x8*)(kp + mt * 1024 + 32);                       \
            z = MFMA16(ka0, qf0v, z);                                                 \
            z = MFMA16(ka1, qf1v, z);                                                 \
            stt[mt] = z;                                                              \
        }                                                                             \
        __builtin_amdgcn_s_setprio(0);                                                \
        if (isdiag) {                                                                 \
            _Pragma("unroll") for (int mt = 0; mt < 4; mt++)                          \
                _Pragma("unroll") for (int r = 0; r < 4; r++) {                       \
                    int kv = (jtv) * 64 + mt * 16 + quad * 4 + r;                     \
                    if (kv > (t0v) + l15) stt[mt][r] = -1e30f;                        \
                }                                                                     \
        }                                                                             \
        float m0_ = fmaxf(fmaxf(stt[0][0], stt[0][1]), stt[0][2]);                    \
        float m1_ = fmaxf(fmaxf(stt[0][3], stt[1][0]), stt[1][1]);                    \
        float m2_ = fmaxf(fmaxf(stt[1][2], stt[1][3]), stt[2][0]);                    \
        float m3_ = fmaxf(fmaxf(stt[2][1], stt[2][2]), stt[2][3]);                    \
        float m4_ = fmaxf(fmaxf(stt[3][0], stt[3][1]), stt[3][2]);                    \
        float mx = fmaxf(fmaxf(fmaxf(m0_, m1_), m2_),                                 \
                         fmaxf(fmaxf(m3_, m4_), stt[3][3]));                          \
        mx = fmaxf(mx, __shfl_xor(mx, 16, 64));                                       \
        mx = fmaxf(mx, __shfl_xor(mx, 32, 64));                                       \
        const bool nodefer = !__all(mx - mi_ <= 8.0f);                                \
        const float mnew = nodefer ? fmaxf(mi_, mx) : mi_;                            \
        float rs = 0.f;                                                               \
        _Pragma("unroll") for (int mt = 0; mt < 4; mt++)                              \
            _Pragma("unroll") for (int r = 0; r < 4; r++) {                           \
                float pv = __builtin_amdgcn_exp2f(stt[mt][r] - mnew);                 \
                stt[mt][r] = pv;                                                      \
                rs += pv;                                                             \
            }                                                                         \
        rs += __shfl_xor(rs, 16, 64);                                                 \
        rs += __shfl_xor(rs, 32, 64);                                                 \
        if (nodefer) {                                                                \
            const float aa = __builtin_amdgcn_exp2f(mi_ - mnew);                      \
            mi_ = mnew;                                                               \
            li_ *= aa;                                                                \
            _Pragma("unroll") for (int mt = 0; mt < 4; mt++)                          \
                _Pragma("unroll") for (int r = 0; r < 4; r++) o_[mt][r] *= aa;        \
        }                                                                             \
        li_ += rs;                                                                    \
        _Pragma("unroll") for (int mt = 0; mt < 4; mt++) {                            \
            bf16x4 pk;                                                                \
            pk[0] = (bf16)stt[mt][0]; pk[1] = (bf16)stt[mt][1];                       \
            pk[2] = (bf16)stt[mt][2]; pk[3] = (bf16)stt[mt][3];                       \
            *(bf16x4*)(psw + l15 * KP2 + mt * 16 + quad * 4) = pk;                    \
        }                                                                             \
        const bf16* vp = vbase + (jtv) * 64;                                          \
        __builtin_amdgcn_s_setprio(1);                                                \
        _Pragma("unroll") for (int kc = 0; kc < 2; kc++) {                            \
            bf16x8 pb = *(const bf16x8*)(psw + l15 * KP2 + kc * 32 + quad * 8);       \
            _Pragma("unroll") for (int mt = 0; mt < 4; mt++) {                        \
                bf16x8 va = *(const bf16x8*)(vp + mt * 32768 + kc * 32);              \
                o_[mt] = MFMA16(va, pb, o_[mt]);                                      \
            }                                                                         \
        }                                                                             \
        __builtin_amdgcn_s_setprio(0);                                                \
    }

    // ---- tile A slots: s in [s0, min(s1, nttA)), jt = s
    {
        const int eA = (s1 < nttA) ? s1 : nttA;
        if (s0 < eA) {
            bf16x8 qf0 = *(const bf16x8*)qpA;
            bf16x8 qf1 = *(const bf16x8*)(qpA + 32);
            for (int s = s0; s < eA; s++) {
                KV_STEP(s, (s == nttA - 1), t0A, qf0, qf1, miA, liA, oA);
            }
        }
    }
    // ---- tile B slots: s in [max(s0, nttA), s1), jt = s - nttA
    {
        const int sB = (s0 > nttA) ? s0 : nttA;
        if (sB < s1) {
            bf16x8 qf0 = *(const bf16x8*)qpB;
            bf16x8 qf1 = *(const bf16x8*)(qpB + 32);
            for (int s = sB; s < s1; s++) {
                KV_STEP(s - nttA, (s == L - 1), t0B, qf0, qf1, miB, liB, oB);
            }
        }
    }

    // ---- merge tile A then tile B (Os region unions with ps)
    #pragma unroll
    for (int tile = 0; tile < 2; tile++) {
        __syncthreads();
        float mi = tile ? miB : miA;
        float li = tile ? liB : liA;
        if (lane < 16) { Ms[w][lane] = mi; Ls[w][lane] = li; }
        #pragma unroll
        for (int mt = 0; mt < 4; mt++) {
            floatx4 ov = tile ? oB[mt] : oA[mt];
            *(floatx4*)(Os + (w * 16 + l15) * OH + mt * 16 + quad * 4) = ov;
        }
        __syncthreads();
        {
            int qq = tid >> 5;               // 0..15
            int h2 = (tid & 31) * 2;         // 0..62
            float Mg = -1e30f;
            #pragma unroll
            for (int u = 0; u < 8; u++) Mg = fmaxf(Mg, Ms[u][qq]);
            float Lg = 0.f, v0 = 0.f, v1 = 0.f;
            #pragma unroll
            for (int u = 0; u < 8; u++) {
                float sw = __builtin_amdgcn_exp2f(Ms[u][qq] - Mg);
                Lg += sw * Ls[u][qq];
                const float* Or = Os + (u * 16 + qq) * OH + h2;
                v0 += sw * Or[0];
                v1 += sw * Or[1];
            }
            float inv = 1.0f / Lg;
            int t0v = tile ? t0B : t0A;
            float* op = out + (size_t)(b * 2048 + t0v + qq) * 64 + h2;
            op[0] = v0 * inv;
            op[1] = v1 * inv;
        }
    }
#undef KV_STEP
}

// ---------------------------------------------------------------------------
extern "C" void kernel_launch(void* const* d_in, const int* in_sizes, int n_in,
                              void* d_out, int out_size, void* d_ws, size_t ws_size,
                              hipStream_t stream) {
    const float* x  = (const float*)d_in[0];
    const float* Wq = (const float*)d_in[1];
    const float* Wk = (const float*)d_in[2];
    const float* Wv = (const float*)d_in[3];
    float* out = (float*)d_out;

    char* ws = (char*)d_ws;
    bf16* wTf = (bf16*)ws;                              // 393216 B + 4 KB slack
    bf16* q   = (bf16*)(ws + 397312);                   // 2 MB
    bf16* k   = (bf16*)(ws + 397312 + 2097152);
    bf16* vT  = (bf16*)(ws + 397312 + 2 * 2097152);     // [b*64+h][2048]

    hipLaunchKernelGGL(prep_w,   dim3(768), dim3(256), 0, stream, Wq, Wk, Wv, wTf);
    hipLaunchKernelGGL(proj_qkv, dim3(512), dim3(256), 0, stream, x, wTf, q, k, vT);
    hipLaunchKernelGGL(flash,    dim3(512), dim3(512), 0, stream, q, k, vT, out);
}

// Round 3
// 140.540 us; speedup vs baseline: 1.0251x; 1.0251x over previous
//
#include <hip/hip_runtime.h>

typedef __bf16 bf16;
typedef __attribute__((ext_vector_type(8))) __bf16 bf16x8;
typedef __attribute__((ext_vector_type(4))) __bf16 bf16x4;
typedef __attribute__((ext_vector_type(4))) float floatx4;

#define MFMA16(a, b, c) __builtin_amdgcn_mfma_f32_16x16x32_bf16((a), (b), (c), 0, 0, 0)

// ---------------------------------------------------------------------------
// Kernel 0: W [1024][64] fp32 x3 -> wTf, FRAGMENT-MAJOR bf16:
//   wTf[(((mt*32 + kc)*4 + q)*16 + l)*8 + j] = A[m = mt*16+l][k = kc*32+q*8+j]
//   where A[m][c] = W_{m/64}[c][m%64].
// ---------------------------------------------------------------------------
__global__ void prep_w(const float* __restrict__ Wq, const float* __restrict__ Wk,
                       const float* __restrict__ Wv, bf16* __restrict__ wTf) {
    int tid = blockIdx.x * 256 + threadIdx.x;   // [0, 196608)
    int j = tid & 7;
    int l = (tid >> 3) & 15;
    int q = (tid >> 7) & 3;
    int kc = (tid >> 9) & 31;
    int mt = tid >> 14;                          // 0..11
    int mat = mt >> 2;
    int h = ((mt & 3) << 4) + l;
    int c = kc * 32 + q * 8 + j;
    const float* W = (mat == 0) ? Wq : (mat == 1) ? Wk : Wv;
    wTf[tid] = (bf16)W[c * 64 + h];
}

// ---------------------------------------------------------------------------
// Kernel 1: QKV projection, TWO-CHUNK pipelined staging. Block = 256 thr
// (4 waves) = ONE 32-row t-tile (512 blocks). All 32 float4 x-loads issue
// back-to-back (round-1 MLP); chunk0 (cols 0-511) stores + 1 barrier, then
// K-steps 0-15 compute WHILE chunk1's 16 loads are in flight (slack = 16
// K-steps >> HBM latency; round-2's 16-chunk depth-3 pipeline stalled here).
// Chunk1 store + 1 barrier + K-steps 16-31. Only 2 barriers total.
// LDS 64 KB [32 rows][2048 B], XOR-swizzled (byte ^= (row&7)<<4, write+read).
// ---------------------------------------------------------------------------
__global__ __launch_bounds__(256, 2) void proj_qkv(const float* __restrict__ x,
                                                   const bf16* __restrict__ wTf,
                                                   bf16* __restrict__ q,
                                                   bf16* __restrict__ k,
                                                   bf16* __restrict__ vT) {
    __shared__ __align__(16) char xsb[32 * 2048];   // 64 KB exact

    const int tid = threadIdx.x;
    const int lane = tid & 63;
    const int w = tid >> 6;          // wave 0..3 = m-group
    const int l15 = lane & 15;
    const int quad = lane >> 4;
    const int T0 = blockIdx.x * 32;

    // stage mapping: thread (r = tid>>4, cm = tid&15) stages rows r and r+16.
    const int r = tid >> 4;
    const int cm = tid & 15;
    const float* g0 = x + (size_t)(T0 + r) * 1024 + cm * 8;
    const float* g1 = x + (size_t)(T0 + r + 16) * 1024 + cm * 8;
    char* ld0 = xsb + r * 2048;
    char* ld1 = xsb + (r + 16) * 2048;
    const int sws = (r & 7) << 4;    // same swizzle for rows r and r+16

#define STC8(ldb, c, f0, f1)                                                    \
    {                                                                            \
        bf16x8 pk;                                                               \
        pk[0] = (bf16)(f0)[0]; pk[1] = (bf16)(f0)[1];                            \
        pk[2] = (bf16)(f0)[2]; pk[3] = (bf16)(f0)[3];                            \
        pk[4] = (bf16)(f1)[0]; pk[5] = (bf16)(f1)[1];                            \
        pk[6] = (bf16)(f1)[2]; pk[7] = (bf16)(f1)[3];                            \
        *(bf16x8*)((ldb) + ((cm * 16 + (c) * 256) ^ sws)) = pk;                  \
    }

    // ---- issue ALL loads back-to-back (32 float4 in flight, max MLP)
    floatx4 fA[8], fB[8], hA[8], hB[8];
    #pragma unroll
    for (int c = 0; c < 4; c++) {
        fA[2*c]   = *(const floatx4*)(g0 + c * 128);
        fA[2*c+1] = *(const floatx4*)(g0 + c * 128 + 4);
        fB[2*c]   = *(const floatx4*)(g1 + c * 128);
        fB[2*c+1] = *(const floatx4*)(g1 + c * 128 + 4);
    }
    #pragma unroll
    for (int c = 0; c < 4; c++) {
        hA[2*c]   = *(const floatx4*)(g0 + 512 + c * 128);
        hA[2*c+1] = *(const floatx4*)(g0 + 512 + c * 128 + 4);
        hB[2*c]   = *(const floatx4*)(g1 + 512 + c * 128);
        hB[2*c+1] = *(const floatx4*)(g1 + 512 + c * 128 + 4);
    }
    // ---- store chunk0 (cols 0-511), one barrier
    #pragma unroll
    for (int c = 0; c < 4; c++) {
        STC8(ld0, c, fA[2*c], fA[2*c+1]);
        STC8(ld1, c, fB[2*c], fB[2*c+1]);
    }
    __syncthreads();

    // ---- compute set-up: depth-2 A prefetch; 6 MFMAs per A-fragment triple.
    floatx4 acc[6] = {};     // [i=mtile 0..2][tt=0..1] flattened i*2+tt
    const bf16* aw0 = wTf + (size_t)(w * 3 + 0) * 16384 + lane * 8;
    const bf16* aw1 = wTf + (size_t)(w * 3 + 1) * 16384 + lane * 8;
    const bf16* aw2 = wTf + (size_t)(w * 3 + 2) * 16384 + lane * 8;
    const char* xr = xsb + l15 * 2048;           // t-row l15 (tt=0); +32768 for tt=1
    const int sx = (l15 & 7) << 4;               // same for row l15+16
    const int q16 = quad * 16;

    bf16x8 a0c = *(const bf16x8*)(aw0);
    bf16x8 a1c = *(const bf16x8*)(aw1);
    bf16x8 a2c = *(const bf16x8*)(aw2);
    bf16x8 a0n = *(const bf16x8*)(aw0 + 512);
    bf16x8 a1n = *(const bf16x8*)(aw1 + 512);
    bf16x8 a2n = *(const bf16x8*)(aw2 + 512);

#define KBODY(kc)                                                               \
    {                                                                            \
        bf16x8 p0 = *(const bf16x8*)(aw0 + ((kc) + 2) * 512);                    \
        bf16x8 p1 = *(const bf16x8*)(aw1 + ((kc) + 2) * 512);                    \
        bf16x8 p2 = *(const bf16x8*)(aw2 + ((kc) + 2) * 512);                    \
        const int o = ((kc) * 64 + q16) ^ sx;                                    \
        bf16x8 b0 = *(const bf16x8*)(xr + o);                                    \
        bf16x8 b1 = *(const bf16x8*)(xr + 32768 + o);                            \
        acc[0] = MFMA16(a0c, b0, acc[0]);                                        \
        acc[1] = MFMA16(a0c, b1, acc[1]);                                        \
        acc[2] = MFMA16(a1c, b0, acc[2]);                                        \
        acc[3] = MFMA16(a1c, b1, acc[3]);                                        \
        acc[4] = MFMA16(a2c, b0, acc[4]);                                        \
        acc[5] = MFMA16(a2c, b1, acc[5]);                                        \
        a0c = a0n; a1c = a1n; a2c = a2n;                                         \
        a0n = p0;  a1n = p1;  a2n = p2;                                          \
    }

    // ---- compute chunk0 (K-steps 0..15) while chunk1 loads fly
    #pragma unroll 4
    for (int kc = 0; kc < 16; kc++) KBODY(kc);

    // ---- store chunk1 (cols 512-1023), one barrier
    #pragma unroll
    for (int c = 4; c < 8; c++) {
        STC8(ld0, c, hA[2*(c-4)], hA[2*(c-4)+1]);
        STC8(ld1, c, hB[2*(c-4)], hB[2*(c-4)+1]);
    }
    __syncthreads();

    // ---- compute chunk1 (K-steps 16..31)
    #pragma unroll 4
    for (int kc = 16; kc < 32; kc++) KBODY(kc);
#undef KBODY
#undef STC8

    // Epilogue. C-layout: (i,r) -> out-row m = (w*3+i)*16 + quad*4 + r
    // (mat = m/64, h = m%64), out-col t = T0 + tt*16 + l15.
    // q gets (1/8)*log2(e) folded (flash softmax runs in base-2).
    #pragma unroll
    for (int i = 0; i < 3; i++) {
        int mtile = w * 3 + i;
        int mat = mtile >> 2;                          // wave-uniform
        int hbase = ((mtile & 3) << 4) + (quad << 2);
        float sc = (mat == 0) ? 0.18033688011112042f : 1.0f;
        #pragma unroll
        for (int tt = 0; tt < 2; tt++) {
            const int t = T0 + tt * 16 + l15;
            floatx4 av = acc[i * 2 + tt];
            bf16x4 pk;
            pk[0] = (bf16)(av[0] * sc);
            pk[1] = (bf16)(av[1] * sc);
            pk[2] = (bf16)(av[2] * sc);
            pk[3] = (bf16)(av[3] * sc);
            if (mat == 0) {
                *(bf16x4*)(q + (size_t)t * 64 + hbase) = pk;
            } else if (mat == 1) {
                *(bf16x4*)(k + (size_t)t * 64 + hbase) = pk;
            } else {
                int bidx = t >> 11, tmod = t & 2047;
                #pragma unroll
                for (int rr = 0; rr < 4; rr++)
                    vT[(size_t)(bidx * 64 + hbase + rr) * 2048 + tmod] = pk[rr];
            }
        }
    }
}

// ---------------------------------------------------------------------------
// Kernel 2: causal flash attention, S^T formulation, uniform two-tile blocks.
// Softmax runs in BASE-2 (log2e folded into q) -> every exp is one v_exp_f32.
// T13 defer-max: when __all(mx - m <= 8) keep old running max and skip the
// O-rescale pass. T5 setprio around MFMA clusters. Max reduction shaped as
// fmax(fmax(a,b),c) triples so clang emits v_max3_f32 (8 ops vs 15).
// ---------------------------------------------------------------------------
#define KP2 72
#define OH 68

__global__ __launch_bounds__(512, 4) void flash(const bf16* __restrict__ q,
                                                const bf16* __restrict__ k,
                                                const bf16* __restrict__ vT,
                                                float* __restrict__ out) {
    __shared__ char smem[8 * 16 * OH * 4];   // union: ps (loop) / Os (merge)
    __shared__ float Ms[8][16], Ls[8][16];
    bf16* psall = (bf16*)smem;
    float* Os = (float*)smem;                // [w][q=16][OH]

    const int b = blockIdx.x & 7;            // batch -> XCD affinity
    const int p = blockIdx.x >> 3;           // 0..63
    const int t0A = p * 16;
    const int t0B = (127 - p) * 16;
    const int nttA = (p >> 2) + 1;
    const int nttB = ((127 - p) >> 2) + 1;
    const int L = nttA + nttB;               // 32..34 for all blocks

    const int tid = threadIdx.x;
    const int w = tid >> 6;
    const int lane = tid & 63;
    const int l15 = lane & 15;
    const int quad = lane >> 4;

    const int s0 = (L * w) >> 3;
    const int s1 = (L * (w + 1)) >> 3;

    const bf16* kbase = k + (size_t)(b * 2048 + l15) * 64 + quad * 8;   // + jt*4096 + mt*1024 + c*32
    const bf16* vbase = vT + (size_t)(b * 64 + l15) * 2048 + quad * 8;  // + mt*32768 + jt*64 + kc*32
    bf16* psw = psall + w * 16 * KP2;

    // Q B-frags: lane n=l15 -> q-row, k = h = quad*8+j (+32)
    const bf16* qpA = q + (size_t)(b * 2048 + t0A + l15) * 64 + quad * 8;
    const bf16* qpB = q + (size_t)(b * 2048 + t0B + l15) * 64 + quad * 8;

    floatx4 oA[4] = {}, oB[4] = {};
    float miA = -1e30f, liA = 0.f, miB = -1e30f, liB = 0.f;

#define KV_STEP(jtv, isdiag, t0v, qf0v, qf1v, mi_, li_, o_)                          \
    {                                                                                 \
        const bf16* kp = kbase + (size_t)(jtv) * 4096;                                \
        floatx4 stt[4];                                                               \
        __builtin_amdgcn_s_setprio(1);                                                \
        _Pragma("unroll") for (int mt = 0; mt < 4; mt++) {                            \
            floatx4 z = {};                                                           \
            bf16x8 ka0 = *(const bf16x8*)(kp + mt * 1024);                            \
            bf16x8 ka1 = *(const bf16x8*)(kp + mt * 1024 + 32);                       \
            z = MFMA16(ka0, qf0v, z);                                                 \
            z = MFMA16(ka1, qf1v, z);                                                 \
            stt[mt] = z;                                                              \
        }                                                                             \
        __builtin_amdgcn_s_setprio(0);                                                \
        if (isdiag) {                                                                 \
            _Pragma("unroll") for (int mt = 0; mt < 4; mt++)                          \
                _Pragma("unroll") for (int rr = 0; rr < 4; rr++) {                    \
                    int kv = (jtv) * 64 + mt * 16 + quad * 4 + rr;                    \
                    if (kv > (t0v) + l15) stt[mt][rr] = -1e30f;                       \
                }                                                                     \
        }                                                                             \
        float m0_ = fmaxf(fmaxf(stt[0][0], stt[0][1]), stt[0][2]);                    \
        float m1_ = fmaxf(fmaxf(stt[0][3], stt[1][0]), stt[1][1]);                    \
        float m2_ = fmaxf(fmaxf(stt[1][2], stt[1][3]), stt[2][0]);                    \
        float m3_ = fmaxf(fmaxf(stt[2][1], stt[2][2]), stt[2][3]);                    \
        float m4_ = fmaxf(fmaxf(stt[3][0], stt[3][1]), stt[3][2]);                    \
        float mx = fmaxf(fmaxf(fmaxf(m0_, m1_), m2_),                                 \
                         fmaxf(fmaxf(m3_, m4_), stt[3][3]));                          \
        mx = fmaxf(mx, __shfl_xor(mx, 16, 64));                                       \
        mx = fmaxf(mx, __shfl_xor(mx, 32, 64));                                       \
        const bool nodefer = !__all(mx - mi_ <= 8.0f);                                \
        const float mnew = nodefer ? fmaxf(mi_, mx) : mi_;                            \
        float rs = 0.f;                                                               \
        _Pragma("unroll") for (int mt = 0; mt < 4; mt++)                              \
            _Pragma("unroll") for (int rr = 0; rr < 4; rr++) {                        \
                float pv = __builtin_amdgcn_exp2f(stt[mt][rr] - mnew);                \
                stt[mt][rr] = pv;                                                     \
                rs += pv;                                                             \
            }                                                                         \
        rs += __shfl_xor(rs, 16, 64);                                                 \
        rs += __shfl_xor(rs, 32, 64);                                                 \
        if (nodefer) {                                                                \
            const float aa = __builtin_amdgcn_exp2f(mi_ - mnew);                      \
            mi_ = mnew;                                                               \
            li_ *= aa;                                                                \
            _Pragma("unroll") for (int mt = 0; mt < 4; mt++)                          \
                _Pragma("unroll") for (int rr = 0; rr < 4; rr++) o_[mt][rr] *= aa;    \
        }                                                                             \
        li_ += rs;                                                                    \
        _Pragma("unroll") for (int mt = 0; mt < 4; mt++) {                            \
            bf16x4 pk;                                                                \
            pk[0] = (bf16)stt[mt][0]; pk[1] = (bf16)stt[mt][1];                       \
            pk[2] = (bf16)stt[mt][2]; pk[3] = (bf16)stt[mt][3];                       \
            *(bf16x4*)(psw + l15 * KP2 + mt * 16 + quad * 4) = pk;                    \
        }                                                                             \
        const bf16* vp = vbase + (jtv) * 64;                                          \
        __builtin_amdgcn_s_setprio(1);                                                \
        _Pragma("unroll") for (int kc = 0; kc < 2; kc++) {                            \
            bf16x8 pb = *(const bf16x8*)(psw + l15 * KP2 + kc * 32 + quad * 8);       \
            _Pragma("unroll") for (int mt = 0; mt < 4; mt++) {                        \
                bf16x8 va = *(const bf16x8*)(vp + mt * 32768 + kc * 32);              \
                o_[mt] = MFMA16(va, pb, o_[mt]);                                      \
            }                                                                         \
        }                                                                             \
        __builtin_amdgcn_s_setprio(0);                                                \
    }

    // ---- tile A slots: s in [s0, min(s1, nttA)), jt = s
    {
        const int eA = (s1 < nttA) ? s1 : nttA;
        if (s0 < eA) {
            bf16x8 qf0 = *(const bf16x8*)qpA;
            bf16x8 qf1 = *(const bf16x8*)(qpA + 32);
            for (int s = s0; s < eA; s++) {
                KV_STEP(s, (s == nttA - 1), t0A, qf0, qf1, miA, liA, oA);
            }
        }
    }
    // ---- tile B slots: s in [max(s0, nttA), s1), jt = s - nttA
    {
        const int sB = (s0 > nttA) ? s0 : nttA;
        if (sB < s1) {
            bf16x8 qf0 = *(const bf16x8*)qpB;
            bf16x8 qf1 = *(const bf16x8*)(qpB + 32);
            for (int s = sB; s < s1; s++) {
                KV_STEP(s - nttA, (s == L - 1), t0B, qf0, qf1, miB, liB, oB);
            }
        }
    }

    // ---- merge tile A then tile B (Os region unions with ps)
    #pragma unroll
    for (int tile = 0; tile < 2; tile++) {
        __syncthreads();
        float mi = tile ? miB : miA;
        float li = tile ? liB : liA;
        if (lane < 16) { Ms[w][lane] = mi; Ls[w][lane] = li; }
        #pragma unroll
        for (int mt = 0; mt < 4; mt++) {
            floatx4 ov = tile ? oB[mt] : oA[mt];
            *(floatx4*)(Os + (w * 16 + l15) * OH + mt * 16 + quad * 4) = ov;
        }
        __syncthreads();
        {
            int qq = tid >> 5;               // 0..15
            int h2 = (tid & 31) * 2;         // 0..62
            float Mg = -1e30f;
            #pragma unroll
            for (int u = 0; u < 8; u++) Mg = fmaxf(Mg, Ms[u][qq]);
            float Lg = 0.f, v0 = 0.f, v1 = 0.f;
            #pragma unroll
            for (int u = 0; u < 8; u++) {
                float sw = __builtin_amdgcn_exp2f(Ms[u][qq] - Mg);
                Lg += sw * Ls[u][qq];
                const float* Or = Os + (u * 16 + qq) * OH + h2;
                v0 += sw * Or[0];
                v1 += sw * Or[1];
            }
            float inv = 1.0f / Lg;
            int t0v = tile ? t0B : t0A;
            float* op = out + (size_t)(b * 2048 + t0v + qq) * 64 + h2;
            op[0] = v0 * inv;
            op[1] = v1 * inv;
        }
    }
#undef KV_STEP
}

// ---------------------------------------------------------------------------
extern "C" void kernel_launch(void* const* d_in, const int* in_sizes, int n_in,
                              void* d_out, int out_size, void* d_ws, size_t ws_size,
                              hipStream_t stream) {
    const float* x  = (const float*)d_in[0];
    const float* Wq = (const float*)d_in[1];
    const float* Wk = (const float*)d_in[2];
    const float* Wv = (const float*)d_in[3];
    float* out = (float*)d_out;

    char* ws = (char*)d_ws;
    bf16* wTf = (bf16*)ws;                              // 393216 B + 4 KB slack
    bf16* q   = (bf16*)(ws + 397312);                   // 2 MB
    bf16* k   = (bf16*)(ws + 397312 + 2097152);
    bf16* vT  = (bf16*)(ws + 397312 + 2 * 2097152);     // [b*64+h][2048]

    hipLaunchKernelGGL(prep_w,   dim3(768), dim3(256), 0, stream, Wq, Wk, Wv, wTf);
    hipLaunchKernelGGL(proj_qkv, dim3(512), dim3(256), 0, stream, x, wTf, q, k, vT);
    hipLaunchKernelGGL(flash,    dim3(512), dim3(512), 0, stream, q, k, vT, out);
}

// Round 4
// 128.106 us; speedup vs baseline: 1.1246x; 1.0971x over previous
//
#include <hip/hip_runtime.h>

typedef __bf16 bf16;
typedef __attribute__((ext_vector_type(8))) __bf16 bf16x8;
typedef __attribute__((ext_vector_type(4))) __bf16 bf16x4;
typedef __attribute__((ext_vector_type(4))) float floatx4;

#define MFMA16(a, b, c) __builtin_amdgcn_mfma_f32_16x16x32_bf16((a), (b), (c), 0, 0, 0)

// ---------------------------------------------------------------------------
// Kernel 0: W [1024][64] fp32 x3 -> wTf, FRAGMENT-MAJOR bf16 (unchanged).
// ---------------------------------------------------------------------------
__global__ void prep_w(const float* __restrict__ Wq, const float* __restrict__ Wk,
                       const float* __restrict__ Wv, bf16* __restrict__ wTf) {
    int tid = blockIdx.x * 256 + threadIdx.x;   // [0, 196608)
    int j = tid & 7;
    int l = (tid >> 3) & 15;
    int q = (tid >> 7) & 3;
    int kc = (tid >> 9) & 31;
    int mt = tid >> 14;                          // 0..11
    int mat = mt >> 2;
    int h = ((mt & 3) << 4) + l;
    int c = kc * 32 + q * 8 + j;
    const float* W = (mat == 0) ? Wq : (mat == 1) ? Wk : Wv;
    wTf[tid] = (bf16)W[c * 64 + h];
}

// ---------------------------------------------------------------------------
// Kernel 1: QKV projection (unchanged from round 3 — at HBM floor).
// ---------------------------------------------------------------------------
__global__ __launch_bounds__(256, 2) void proj_qkv(const float* __restrict__ x,
                                                   const bf16* __restrict__ wTf,
                                                   bf16* __restrict__ q,
                                                   bf16* __restrict__ k,
                                                   bf16* __restrict__ vT) {
    __shared__ __align__(16) char xsb[32 * 2048];   // 64 KB exact

    const int tid = threadIdx.x;
    const int lane = tid & 63;
    const int w = tid >> 6;          // wave 0..3 = m-group
    const int l15 = lane & 15;
    const int quad = lane >> 4;
    const int T0 = blockIdx.x * 32;

    const int r = tid >> 4;
    const int cm = tid & 15;
    const float* g0 = x + (size_t)(T0 + r) * 1024 + cm * 8;
    const float* g1 = x + (size_t)(T0 + r + 16) * 1024 + cm * 8;
    char* ld0 = xsb + r * 2048;
    char* ld1 = xsb + (r + 16) * 2048;
    const int sws = (r & 7) << 4;

#define STC8(ldb, c, f0, f1)                                                    \
    {                                                                            \
        bf16x8 pk;                                                               \
        pk[0] = (bf16)(f0)[0]; pk[1] = (bf16)(f0)[1];                            \
        pk[2] = (bf16)(f0)[2]; pk[3] = (bf16)(f0)[3];                            \
        pk[4] = (bf16)(f1)[0]; pk[5] = (bf16)(f1)[1];                            \
        pk[6] = (bf16)(f1)[2]; pk[7] = (bf16)(f1)[3];                            \
        *(bf16x8*)((ldb) + ((cm * 16 + (c) * 256) ^ sws)) = pk;                  \
    }

    floatx4 fA[8], fB[8], hA[8], hB[8];
    #pragma unroll
    for (int c = 0; c < 4; c++) {
        fA[2*c]   = *(const floatx4*)(g0 + c * 128);
        fA[2*c+1] = *(const floatx4*)(g0 + c * 128 + 4);
        fB[2*c]   = *(const floatx4*)(g1 + c * 128);
        fB[2*c+1] = *(const floatx4*)(g1 + c * 128 + 4);
    }
    #pragma unroll
    for (int c = 0; c < 4; c++) {
        hA[2*c]   = *(const floatx4*)(g0 + 512 + c * 128);
        hA[2*c+1] = *(const floatx4*)(g0 + 512 + c * 128 + 4);
        hB[2*c]   = *(const floatx4*)(g1 + 512 + c * 128);
        hB[2*c+1] = *(const floatx4*)(g1 + 512 + c * 128 + 4);
    }
    #pragma unroll
    for (int c = 0; c < 4; c++) {
        STC8(ld0, c, fA[2*c], fA[2*c+1]);
        STC8(ld1, c, fB[2*c], fB[2*c+1]);
    }
    __syncthreads();

    floatx4 acc[6] = {};
    const bf16* aw0 = wTf + (size_t)(w * 3 + 0) * 16384 + lane * 8;
    const bf16* aw1 = wTf + (size_t)(w * 3 + 1) * 16384 + lane * 8;
    const bf16* aw2 = wTf + (size_t)(w * 3 + 2) * 16384 + lane * 8;
    const char* xr = xsb + l15 * 2048;
    const int sx = (l15 & 7) << 4;
    const int q16 = quad * 16;

    bf16x8 a0c = *(const bf16x8*)(aw0);
    bf16x8 a1c = *(const bf16x8*)(aw1);
    bf16x8 a2c = *(const bf16x8*)(aw2);
    bf16x8 a0n = *(const bf16x8*)(aw0 + 512);
    bf16x8 a1n = *(const bf16x8*)(aw1 + 512);
    bf16x8 a2n = *(const bf16x8*)(aw2 + 512);

#define KBODY(kc)                                                               \
    {                                                                            \
        bf16x8 p0 = *(const bf16x8*)(aw0 + ((kc) + 2) * 512);                    \
        bf16x8 p1 = *(const bf16x8*)(aw1 + ((kc) + 2) * 512);                    \
        bf16x8 p2 = *(const bf16x8*)(aw2 + ((kc) + 2) * 512);                    \
        const int o = ((kc) * 64 + q16) ^ sx;                                    \
        bf16x8 b0 = *(const bf16x8*)(xr + o);                                    \
        bf16x8 b1 = *(const bf16x8*)(xr + 32768 + o);                            \
        acc[0] = MFMA16(a0c, b0, acc[0]);                                        \
        acc[1] = MFMA16(a0c, b1, acc[1]);                                        \
        acc[2] = MFMA16(a1c, b0, acc[2]);                                        \
        acc[3] = MFMA16(a1c, b1, acc[3]);                                        \
        acc[4] = MFMA16(a2c, b0, acc[4]);                                        \
        acc[5] = MFMA16(a2c, b1, acc[5]);                                        \
        a0c = a0n; a1c = a1n; a2c = a2n;                                         \
        a0n = p0;  a1n = p1;  a2n = p2;                                          \
    }

    #pragma unroll 4
    for (int kc = 0; kc < 16; kc++) KBODY(kc);

    #pragma unroll
    for (int c = 4; c < 8; c++) {
        STC8(ld0, c, hA[2*(c-4)], hA[2*(c-4)+1]);
        STC8(ld1, c, hB[2*(c-4)], hB[2*(c-4)+1]);
    }
    __syncthreads();

    #pragma unroll 4
    for (int kc = 16; kc < 32; kc++) KBODY(kc);
#undef KBODY
#undef STC8

    #pragma unroll
    for (int i = 0; i < 3; i++) {
        int mtile = w * 3 + i;
        int mat = mtile >> 2;
        int hbase = ((mtile & 3) << 4) + (quad << 2);
        float sc = (mat == 0) ? 0.18033688011112042f : 1.0f;
        #pragma unroll
        for (int tt = 0; tt < 2; tt++) {
            const int t = T0 + tt * 16 + l15;
            floatx4 av = acc[i * 2 + tt];
            bf16x4 pk;
            pk[0] = (bf16)(av[0] * sc);
            pk[1] = (bf16)(av[1] * sc);
            pk[2] = (bf16)(av[2] * sc);
            pk[3] = (bf16)(av[3] * sc);
            if (mat == 0) {
                *(bf16x4*)(q + (size_t)t * 64 + hbase) = pk;
            } else if (mat == 1) {
                *(bf16x4*)(k + (size_t)t * 64 + hbase) = pk;
            } else {
                int bidx = t >> 11, tmod = t & 2047;
                #pragma unroll
                for (int rr = 0; rr < 4; rr++)
                    vT[(size_t)(bidx * 64 + hbase + rr) * 2048 + tmod] = pk[rr];
            }
        }
    }
}

// ---------------------------------------------------------------------------
// Kernel 2: causal flash attention with 2-WAY K/V SHARING.
// Block = quad of q-tiles {2j, 2j+1, 126-2j, 127-2j} (adjacent pairs have
// IDENTICAL causal KV ranges since (2j)>>2 == (2j+1)>>2). Per KV slot, ONE
// wave loads the K tile once into registers, computes QK^T for BOTH paired
// tiles, then loads V once feeding both PV accumulations -> K/V L2 traffic
// and VMEM instruction count HALVE (270 -> ~137 MB grid-wide).
// Work per block = NN + NF = (j>>1)+((63-j)>>1)+2 = 33 slots, uniform for
// all blocks. 256 blocks x 512 thr (1 block/CU, 2 waves/SIMD); 4 accumulator
// sets/wave -> __launch_bounds__(512,2). Softmax base-2, defer-max, setprio
// retained. Merge = 4 rounds over the quad's tiles.
// ---------------------------------------------------------------------------
#define KP2 72
#define OH 68
#define PSB (16 * KP2)

__global__ __launch_bounds__(512, 2) void flash(const bf16* __restrict__ q,
                                                const bf16* __restrict__ k,
                                                const bf16* __restrict__ vT,
                                                float* __restrict__ out) {
    __shared__ char smem[36864];             // union: ps (2 regions/wave) / Os
    __shared__ float Ms[8][16], Ls[8][16];
    bf16* psall = (bf16*)smem;
    float* Os = (float*)smem;                // [w][q=16][OH]

    const int b = blockIdx.x & 7;            // batch -> XCD affinity
    const int j = blockIdx.x >> 3;           // 0..31
    const int Tn0 = 32 * j;                  // near pair: tiles 2j, 2j+1
    const int Tn1 = Tn0 + 16;
    const int Tf0 = (126 - 2 * j) * 16;      // far pair: tiles 126-2j, 127-2j
    const int Tf1 = Tf0 + 16;
    const int NN = (j >> 1) + 1;             // near-pair KV range (tiles of 64)
    const int NF = ((63 - j) >> 1) + 1;      // far-pair KV range
    const int L = NN + NF;                   // == 33 for every block

    const int tid = threadIdx.x;
    const int w = tid >> 6;
    const int lane = tid & 63;
    const int l15 = lane & 15;
    const int quad = lane >> 4;

    const int u0 = (L * w) >> 3;
    const int u1 = (L * (w + 1)) >> 3;

    const bf16* kbase = k + (size_t)(b * 2048 + l15) * 64 + quad * 8;   // + jt*4096 + mt*1024 + c*32
    const bf16* vbase = vT + (size_t)(b * 64 + l15) * 2048 + quad * 8;  // + mt*32768 + jt*64 + kc*32
    bf16* pswa = psall + w * 2 * PSB;
    bf16* pswb = pswa + PSB;

    const bf16* qn0 = q + (size_t)(b * 2048 + Tn0 + l15) * 64 + quad * 8;
    const bf16* qn1 = q + (size_t)(b * 2048 + Tn1 + l15) * 64 + quad * 8;
    const bf16* qx0 = q + (size_t)(b * 2048 + Tf0 + l15) * 64 + quad * 8;
    const bf16* qx1 = q + (size_t)(b * 2048 + Tf1 + l15) * 64 + quad * 8;

    floatx4 o0[4] = {}, o1[4] = {}, o2[4] = {}, o3[4] = {};
    float mm0 = -1e30f, ll0 = 0.f, mm1 = -1e30f, ll1 = 0.f;
    float mm2 = -1e30f, ll2 = 0.f, mm3 = -1e30f, ll3 = 0.f;

// softmax over stt (one q-tile's 16 S values/lane), online update, ps write
#define SMPART(mi_, li_, o_, pswX)                                                   \
    {                                                                                 \
        float x0_ = fmaxf(fmaxf(stt[0][0], stt[0][1]), stt[0][2]);                    \
        float x1_ = fmaxf(fmaxf(stt[0][3], stt[1][0]), stt[1][1]);                    \
        float x2_ = fmaxf(fmaxf(stt[1][2], stt[1][3]), stt[2][0]);                    \
        float x3_ = fmaxf(fmaxf(stt[2][1], stt[2][2]), stt[2][3]);                    \
        float x4_ = fmaxf(fmaxf(stt[3][0], stt[3][1]), stt[3][2]);                    \
        float mx_ = fmaxf(fmaxf(fmaxf(x0_, x1_), x2_),                                \
                          fmaxf(fmaxf(x3_, x4_), stt[3][3]));                         \
        mx_ = fmaxf(mx_, __shfl_xor(mx_, 16, 64));                                    \
        mx_ = fmaxf(mx_, __shfl_xor(mx_, 32, 64));                                    \
        const bool nd_ = !__all(mx_ - mi_ <= 8.0f);                                   \
        const float mn_ = nd_ ? fmaxf(mi_, mx_) : mi_;                                \
        float rs_ = 0.f;                                                              \
        _Pragma("unroll") for (int mt_ = 0; mt_ < 4; mt_++)                           \
            _Pragma("unroll") for (int rr_ = 0; rr_ < 4; rr_++) {                     \
                float pv_ = __builtin_amdgcn_exp2f(stt[mt_][rr_] - mn_);              \
                stt[mt_][rr_] = pv_;                                                  \
                rs_ += pv_;                                                           \
            }                                                                         \
        rs_ += __shfl_xor(rs_, 16, 64);                                               \
        rs_ += __shfl_xor(rs_, 32, 64);                                               \
        if (nd_) {                                                                    \
            const float aa_ = __builtin_amdgcn_exp2f(mi_ - mn_);                      \
            mi_ = mn_;                                                                \
            li_ *= aa_;                                                               \
            _Pragma("unroll") for (int mt_ = 0; mt_ < 4; mt_++)                       \
                _Pragma("unroll") for (int rr_ = 0; rr_ < 4; rr_++) o_[mt_][rr_] *= aa_; \
        }                                                                             \
        li_ += rs_;                                                                   \
        _Pragma("unroll") for (int mt_ = 0; mt_ < 4; mt_++) {                         \
            bf16x4 pk_;                                                               \
            pk_[0] = (bf16)stt[mt_][0]; pk_[1] = (bf16)stt[mt_][1];                   \
            pk_[2] = (bf16)stt[mt_][2]; pk_[3] = (bf16)stt[mt_][3];                   \
            *(bf16x4*)((pswX) + l15 * KP2 + mt_ * 16 + quad * 4) = pk_;               \
        }                                                                             \
    }

// one KV slot, TWO paired q-tiles sharing the K and V tile reads
#define KV_STEP2(jtv, isdiag, T0a_, T0b_, qa0_, qa1_, qb0_, qb1_,                     \
                 m_a, l_a, o_a, m_b, l_b, o_b)                                        \
    {                                                                                 \
        const bf16* kp_ = kbase + (size_t)(jtv) * 4096;                               \
        bf16x8 kv0_ = *(const bf16x8*)(kp_);                                          \
        bf16x8 kv1_ = *(const bf16x8*)(kp_ + 32);                                     \
        bf16x8 kv2_ = *(const bf16x8*)(kp_ + 1024);                                   \
        bf16x8 kv3_ = *(const bf16x8*)(kp_ + 1024 + 32);                              \
        bf16x8 kv4_ = *(const bf16x8*)(kp_ + 2048);                                   \
        bf16x8 kv5_ = *(const bf16x8*)(kp_ + 2048 + 32);                              \
        bf16x8 kv6_ = *(const bf16x8*)(kp_ + 3072);                                   \
        bf16x8 kv7_ = *(const bf16x8*)(kp_ + 3072 + 32);                              \
        floatx4 stt[4];                                                               \
        __builtin_amdgcn_s_setprio(1);                                                \
        { floatx4 z_ = {}; z_ = MFMA16(kv0_, qa0_, z_); z_ = MFMA16(kv1_, qa1_, z_); stt[0] = z_; } \
        { floatx4 z_ = {}; z_ = MFMA16(kv2_, qa0_, z_); z_ = MFMA16(kv3_, qa1_, z_); stt[1] = z_; } \
        { floatx4 z_ = {}; z_ = MFMA16(kv4_, qa0_, z_); z_ = MFMA16(kv5_, qa1_, z_); stt[2] = z_; } \
        { floatx4 z_ = {}; z_ = MFMA16(kv6_, qa0_, z_); z_ = MFMA16(kv7_, qa1_, z_); stt[3] = z_; } \
        __builtin_amdgcn_s_setprio(0);                                                \
        if (isdiag) {                                                                 \
            _Pragma("unroll") for (int mt_ = 0; mt_ < 4; mt_++)                       \
                _Pragma("unroll") for (int rr_ = 0; rr_ < 4; rr_++) {                 \
                    int kv_ = (jtv) * 64 + mt_ * 16 + quad * 4 + rr_;                 \
                    if (kv_ > (T0a_) + l15) stt[mt_][rr_] = -1e30f;                   \
                }                                                                     \
        }                                                                             \
        SMPART(m_a, l_a, o_a, pswa);                                                  \
        __builtin_amdgcn_s_setprio(1);                                                \
        { floatx4 z_ = {}; z_ = MFMA16(kv0_, qb0_, z_); z_ = MFMA16(kv1_, qb1_, z_); stt[0] = z_; } \
        { floatx4 z_ = {}; z_ = MFMA16(kv2_, qb0_, z_); z_ = MFMA16(kv3_, qb1_, z_); stt[1] = z_; } \
        { floatx4 z_ = {}; z_ = MFMA16(kv4_, qb0_, z_); z_ = MFMA16(kv5_, qb1_, z_); stt[2] = z_; } \
        { floatx4 z_ = {}; z_ = MFMA16(kv6_, qb0_, z_); z_ = MFMA16(kv7_, qb1_, z_); stt[3] = z_; } \
        __builtin_amdgcn_s_setprio(0);                                                \
        if (isdiag) {                                                                 \
            _Pragma("unroll") for (int mt_ = 0; mt_ < 4; mt_++)                       \
                _Pragma("unroll") for (int rr_ = 0; rr_ < 4; rr_++) {                 \
                    int kv_ = (jtv) * 64 + mt_ * 16 + quad * 4 + rr_;                 \
                    if (kv_ > (T0b_) + l15) stt[mt_][rr_] = -1e30f;                   \
                }                                                                     \
        }                                                                             \
        SMPART(m_b, l_b, o_b, pswb);                                                  \
        const bf16* vp_ = vbase + (size_t)(jtv) * 64;                                 \
        bf16x8 pa0_ = *(const bf16x8*)(pswa + l15 * KP2 + quad * 8);                  \
        bf16x8 pa1_ = *(const bf16x8*)(pswa + l15 * KP2 + 32 + quad * 8);             \
        bf16x8 pb0_ = *(const bf16x8*)(pswb + l15 * KP2 + quad * 8);                  \
        bf16x8 pb1_ = *(const bf16x8*)(pswb + l15 * KP2 + 32 + quad * 8);             \
        __builtin_amdgcn_s_setprio(1);                                                \
        _Pragma("unroll") for (int mt_ = 0; mt_ < 4; mt_++) {                         \
            bf16x8 v0_ = *(const bf16x8*)(vp_ + mt_ * 32768);                         \
            bf16x8 v1_ = *(const bf16x8*)(vp_ + mt_ * 32768 + 32);                    \
            o_a[mt_] = MFMA16(v0_, pa0_, o_a[mt_]);                                   \
            o_a[mt_] = MFMA16(v1_, pa1_, o_a[mt_]);                                   \
            o_b[mt_] = MFMA16(v0_, pb0_, o_b[mt_]);                                   \
            o_b[mt_] = MFMA16(v1_, pb1_, o_b[mt_]);                                   \
        }                                                                             \
        __builtin_amdgcn_s_setprio(0);                                                \
    }

    // ---- near-pair slots: s in [u0, min(u1, NN)), jt = s
    {
        const int e = (u1 < NN) ? u1 : NN;
        if (u0 < e) {
            bf16x8 qa0 = *(const bf16x8*)qn0;
            bf16x8 qa1 = *(const bf16x8*)(qn0 + 32);
            bf16x8 qb0 = *(const bf16x8*)qn1;
            bf16x8 qb1 = *(const bf16x8*)(qn1 + 32);
            for (int s = u0; s < e; s++) {
                KV_STEP2(s, (s == NN - 1), Tn0, Tn1, qa0, qa1, qb0, qb1,
                         mm0, ll0, o0, mm1, ll1, o1);
            }
        }
    }
    // ---- far-pair slots: s in [max(u0, NN), u1), jt = s - NN
    {
        const int sB = (u0 > NN) ? u0 : NN;
        if (sB < u1) {
            bf16x8 qa0 = *(const bf16x8*)qx0;
            bf16x8 qa1 = *(const bf16x8*)(qx0 + 32);
            bf16x8 qb0 = *(const bf16x8*)qx1;
            bf16x8 qb1 = *(const bf16x8*)(qx1 + 32);
            for (int s = sB; s < u1; s++) {
                KV_STEP2(s - NN, (s == L - 1), Tf0, Tf1, qa0, qa1, qb0, qb1,
                         mm2, ll2, o2, mm3, ll3, o3);
            }
        }
    }

    // ---- merge: 4 rounds over the quad's tiles (Os unions with ps)
    #pragma unroll
    for (int r = 0; r < 4; r++) {
        __syncthreads();
        float mi = (r == 0) ? mm0 : (r == 1) ? mm1 : (r == 2) ? mm2 : mm3;
        float li = (r == 0) ? ll0 : (r == 1) ? ll1 : (r == 2) ? ll2 : ll3;
        if (lane < 16) { Ms[w][lane] = mi; Ls[w][lane] = li; }
        #pragma unroll
        for (int mt = 0; mt < 4; mt++) {
            floatx4 ov = (r == 0) ? o0[mt] : (r == 1) ? o1[mt] : (r == 2) ? o2[mt] : o3[mt];
            *(floatx4*)(Os + (w * 16 + l15) * OH + mt * 16 + quad * 4) = ov;
        }
        __syncthreads();
        {
            int qq = tid >> 5;               // 0..15
            int h2 = (tid & 31) * 2;         // 0..62
            float Mg = -1e30f;
            #pragma unroll
            for (int u = 0; u < 8; u++) Mg = fmaxf(Mg, Ms[u][qq]);
            float Lg = 0.f, v0 = 0.f, v1 = 0.f;
            #pragma unroll
            for (int u = 0; u < 8; u++) {
                float sw = __builtin_amdgcn_exp2f(Ms[u][qq] - Mg);
                Lg += sw * Ls[u][qq];
                const float* Or = Os + (u * 16 + qq) * OH + h2;
                v0 += sw * Or[0];
                v1 += sw * Or[1];
            }
            float inv = 1.0f / Lg;
            int T0v = (r == 0) ? Tn0 : (r == 1) ? Tn1 : (r == 2) ? Tf0 : Tf1;
            float* op = out + (size_t)(b * 2048 + T0v + qq) * 64 + h2;
            op[0] = v0 * inv;
            op[1] = v1 * inv;
        }
    }
#undef KV_STEP2
#undef SMPART
}

// ---------------------------------------------------------------------------
extern "C" void kernel_launch(void* const* d_in, const int* in_sizes, int n_in,
                              void* d_out, int out_size, void* d_ws, size_t ws_size,
                              hipStream_t stream) {
    const float* x  = (const float*)d_in[0];
    const float* Wq = (const float*)d_in[1];
    const float* Wk = (const float*)d_in[2];
    const float* Wv = (const float*)d_in[3];
    float* out = (float*)d_out;

    char* ws = (char*)d_ws;
    bf16* wTf = (bf16*)ws;                              // 393216 B + 4 KB slack
    bf16* q   = (bf16*)(ws + 397312);                   // 2 MB
    bf16* k   = (bf16*)(ws + 397312 + 2097152);
    bf16* vT  = (bf16*)(ws + 397312 + 2 * 2097152);     // [b*64+h][2048]

    hipLaunchKernelGGL(prep_w,   dim3(768), dim3(256), 0, stream, Wq, Wk, Wv, wTf);
    hipLaunchKernelGGL(proj_qkv, dim3(512), dim3(256), 0, stream, x, wTf, q, k, vT);
    hipLaunchKernelGGL(flash,    dim3(256), dim3(512), 0, stream, q, k, vT, out);
}

// Round 5
// 127.786 us; speedup vs baseline: 1.1274x; 1.0025x over previous
//
#include <hip/hip_runtime.h>

typedef __bf16 bf16;
typedef __attribute__((ext_vector_type(8))) __bf16 bf16x8;
typedef __attribute__((ext_vector_type(4))) __bf16 bf16x4;
typedef __attribute__((ext_vector_type(4))) float floatx4;

#define MFMA16(a, b, c) __builtin_amdgcn_mfma_f32_16x16x32_bf16((a), (b), (c), 0, 0, 0)

// ---------------------------------------------------------------------------
// Kernel 0: W [1024][64] fp32 x3 -> wTf, FRAGMENT-MAJOR bf16 (unchanged).
// ---------------------------------------------------------------------------
__global__ void prep_w(const float* __restrict__ Wq, const float* __restrict__ Wk,
                       const float* __restrict__ Wv, bf16* __restrict__ wTf) {
    int tid = blockIdx.x * 256 + threadIdx.x;   // [0, 196608)
    int j = tid & 7;
    int l = (tid >> 3) & 15;
    int q = (tid >> 7) & 3;
    int kc = (tid >> 9) & 31;
    int mt = tid >> 14;                          // 0..11
    int mat = mt >> 2;
    int h = ((mt & 3) << 4) + l;
    int c = kc * 32 + q * 8 + j;
    const float* W = (mat == 0) ? Wq : (mat == 1) ? Wk : Wv;
    wTf[tid] = (bf16)W[c * 64 + h];
}

// ---------------------------------------------------------------------------
// Kernel 1: QKV projection (unchanged — at HBM floor).
// ---------------------------------------------------------------------------
__global__ __launch_bounds__(256, 2) void proj_qkv(const float* __restrict__ x,
                                                   const bf16* __restrict__ wTf,
                                                   bf16* __restrict__ q,
                                                   bf16* __restrict__ k,
                                                   bf16* __restrict__ vT) {
    __shared__ __align__(16) char xsb[32 * 2048];   // 64 KB exact

    const int tid = threadIdx.x;
    const int lane = tid & 63;
    const int w = tid >> 6;          // wave 0..3 = m-group
    const int l15 = lane & 15;
    const int quad = lane >> 4;
    const int T0 = blockIdx.x * 32;

    const int r = tid >> 4;
    const int cm = tid & 15;
    const float* g0 = x + (size_t)(T0 + r) * 1024 + cm * 8;
    const float* g1 = x + (size_t)(T0 + r + 16) * 1024 + cm * 8;
    char* ld0 = xsb + r * 2048;
    char* ld1 = xsb + (r + 16) * 2048;
    const int sws = (r & 7) << 4;

#define STC8(ldb, c, f0, f1)                                                    \
    {                                                                            \
        bf16x8 pk;                                                               \
        pk[0] = (bf16)(f0)[0]; pk[1] = (bf16)(f0)[1];                            \
        pk[2] = (bf16)(f0)[2]; pk[3] = (bf16)(f0)[3];                            \
        pk[4] = (bf16)(f1)[0]; pk[5] = (bf16)(f1)[1];                            \
        pk[6] = (bf16)(f1)[2]; pk[7] = (bf16)(f1)[3];                            \
        *(bf16x8*)((ldb) + ((cm * 16 + (c) * 256) ^ sws)) = pk;                  \
    }

    floatx4 fA[8], fB[8], hA[8], hB[8];
    #pragma unroll
    for (int c = 0; c < 4; c++) {
        fA[2*c]   = *(const floatx4*)(g0 + c * 128);
        fA[2*c+1] = *(const floatx4*)(g0 + c * 128 + 4);
        fB[2*c]   = *(const floatx4*)(g1 + c * 128);
        fB[2*c+1] = *(const floatx4*)(g1 + c * 128 + 4);
    }
    #pragma unroll
    for (int c = 0; c < 4; c++) {
        hA[2*c]   = *(const floatx4*)(g0 + 512 + c * 128);
        hA[2*c+1] = *(const floatx4*)(g0 + 512 + c * 128 + 4);
        hB[2*c]   = *(const floatx4*)(g1 + 512 + c * 128);
        hB[2*c+1] = *(const floatx4*)(g1 + 512 + c * 128 + 4);
    }
    #pragma unroll
    for (int c = 0; c < 4; c++) {
        STC8(ld0, c, fA[2*c], fA[2*c+1]);
        STC8(ld1, c, fB[2*c], fB[2*c+1]);
    }
    __syncthreads();

    floatx4 acc[6] = {};
    const bf16* aw0 = wTf + (size_t)(w * 3 + 0) * 16384 + lane * 8;
    const bf16* aw1 = wTf + (size_t)(w * 3 + 1) * 16384 + lane * 8;
    const bf16* aw2 = wTf + (size_t)(w * 3 + 2) * 16384 + lane * 8;
    const char* xr = xsb + l15 * 2048;
    const int sx = (l15 & 7) << 4;
    const int q16 = quad * 16;

    bf16x8 a0c = *(const bf16x8*)(aw0);
    bf16x8 a1c = *(const bf16x8*)(aw1);
    bf16x8 a2c = *(const bf16x8*)(aw2);
    bf16x8 a0n = *(const bf16x8*)(aw0 + 512);
    bf16x8 a1n = *(const bf16x8*)(aw1 + 512);
    bf16x8 a2n = *(const bf16x8*)(aw2 + 512);

#define KBODY(kc)                                                               \
    {                                                                            \
        bf16x8 p0 = *(const bf16x8*)(aw0 + ((kc) + 2) * 512);                    \
        bf16x8 p1 = *(const bf16x8*)(aw1 + ((kc) + 2) * 512);                    \
        bf16x8 p2 = *(const bf16x8*)(aw2 + ((kc) + 2) * 512);                    \
        const int o = ((kc) * 64 + q16) ^ sx;                                    \
        bf16x8 b0 = *(const bf16x8*)(xr + o);                                    \
        bf16x8 b1 = *(const bf16x8*)(xr + 32768 + o);                            \
        acc[0] = MFMA16(a0c, b0, acc[0]);                                        \
        acc[1] = MFMA16(a0c, b1, acc[1]);                                        \
        acc[2] = MFMA16(a1c, b0, acc[2]);                                        \
        acc[3] = MFMA16(a1c, b1, acc[3]);                                        \
        acc[4] = MFMA16(a2c, b0, acc[4]);                                        \
        acc[5] = MFMA16(a2c, b1, acc[5]);                                        \
        a0c = a0n; a1c = a1n; a2c = a2n;                                         \
        a0n = p0;  a1n = p1;  a2n = p2;                                          \
    }

    #pragma unroll 4
    for (int kc = 0; kc < 16; kc++) KBODY(kc);

    #pragma unroll
    for (int c = 4; c < 8; c++) {
        STC8(ld0, c, hA[2*(c-4)], hA[2*(c-4)+1]);
        STC8(ld1, c, hB[2*(c-4)], hB[2*(c-4)+1]);
    }
    __syncthreads();

    #pragma unroll 4
    for (int kc = 16; kc < 32; kc++) KBODY(kc);
#undef KBODY
#undef STC8

    #pragma unroll
    for (int i = 0; i < 3; i++) {
        int mtile = w * 3 + i;
        int mat = mtile >> 2;
        int hbase = ((mtile & 3) << 4) + (quad << 2);
        float sc = (mat == 0) ? 0.18033688011112042f : 1.0f;
        #pragma unroll
        for (int tt = 0; tt < 2; tt++) {
            const int t = T0 + tt * 16 + l15;
            floatx4 av = acc[i * 2 + tt];
            bf16x4 pk;
            pk[0] = (bf16)(av[0] * sc);
            pk[1] = (bf16)(av[1] * sc);
            pk[2] = (bf16)(av[2] * sc);
            pk[3] = (bf16)(av[3] * sc);
            if (mat == 0) {
                *(bf16x4*)(q + (size_t)t * 64 + hbase) = pk;
            } else if (mat == 1) {
                *(bf16x4*)(k + (size_t)t * 64 + hbase) = pk;
            } else {
                int bidx = t >> 11, tmod = t & 2047;
                #pragma unroll
                for (int rr = 0; rr < 4; rr++)
                    vT[(size_t)(bidx * 64 + hbase + rr) * 2048 + tmod] = pk[rr];
            }
        }
    }
}

// ---------------------------------------------------------------------------
// Kernel 2: causal flash attention, 2-way K/V sharing + LATENCY SCHEDULING.
// vs round 4: (1) V loads issue at the TOP of each slot (before QK-a) so
// their L2 latency hides under 16 QK MFMAs + 2 softmax passes (the setprio
// intrinsics fence the scheduler, so the compiler could NOT hoist them);
// (2) depth-1 K prefetch: kc regs are re-loaded with slot s+1's K tile
// immediately after QK-b (their last use) — loads fly during SMPART-b + PV
// + next slot's V loads instead of stalling the next QK-a.
// VGPR ~200 peak, under the 256 cap of __launch_bounds__(512,2).
// ---------------------------------------------------------------------------
#define KP2 72
#define OH 68
#define PSB (16 * KP2)

__global__ __launch_bounds__(512, 2) void flash(const bf16* __restrict__ q,
                                                const bf16* __restrict__ k,
                                                const bf16* __restrict__ vT,
                                                float* __restrict__ out) {
    __shared__ char smem[36864];             // union: ps (2 regions/wave) / Os
    __shared__ float Ms[8][16], Ls[8][16];
    bf16* psall = (bf16*)smem;
    float* Os = (float*)smem;                // [w][q=16][OH]

    const int b = blockIdx.x & 7;            // batch -> XCD affinity
    const int j = blockIdx.x >> 3;           // 0..31
    const int Tn0 = 32 * j;                  // near pair: tiles 2j, 2j+1
    const int Tn1 = Tn0 + 16;
    const int Tf0 = (126 - 2 * j) * 16;      // far pair: tiles 126-2j, 127-2j
    const int Tf1 = Tf0 + 16;
    const int NN = (j >> 1) + 1;             // near-pair KV range (tiles of 64)
    const int NF = ((63 - j) >> 1) + 1;      // far-pair KV range
    const int L = NN + NF;                   // == 33 for every block

    const int tid = threadIdx.x;
    const int w = tid >> 6;
    const int lane = tid & 63;
    const int l15 = lane & 15;
    const int quad = lane >> 4;

    const int u0 = (L * w) >> 3;
    const int u1 = (L * (w + 1)) >> 3;

    const bf16* kbase = k + (size_t)(b * 2048 + l15) * 64 + quad * 8;   // + jt*4096 + mt*1024 + c*32
    const bf16* vbase = vT + (size_t)(b * 64 + l15) * 2048 + quad * 8;  // + mt*32768 + jt*64 + kc*32
    bf16* pswa = psall + w * 2 * PSB;
    bf16* pswb = pswa + PSB;

    const bf16* qn0 = q + (size_t)(b * 2048 + Tn0 + l15) * 64 + quad * 8;
    const bf16* qn1 = q + (size_t)(b * 2048 + Tn1 + l15) * 64 + quad * 8;
    const bf16* qx0 = q + (size_t)(b * 2048 + Tf0 + l15) * 64 + quad * 8;
    const bf16* qx1 = q + (size_t)(b * 2048 + Tf1 + l15) * 64 + quad * 8;

    floatx4 o0[4] = {}, o1[4] = {}, o2[4] = {}, o3[4] = {};
    float mm0 = -1e30f, ll0 = 0.f, mm1 = -1e30f, ll1 = 0.f;
    float mm2 = -1e30f, ll2 = 0.f, mm3 = -1e30f, ll3 = 0.f;

// load one K tile (8 x bf16x8) into named regs
#define LOADK(jtv)                                                                   \
    {                                                                                 \
        const bf16* kp_ = kbase + (size_t)(jtv) * 4096;                               \
        kc0_ = *(const bf16x8*)(kp_);                                                 \
        kc1_ = *(const bf16x8*)(kp_ + 32);                                            \
        kc2_ = *(const bf16x8*)(kp_ + 1024);                                          \
        kc3_ = *(const bf16x8*)(kp_ + 1056);                                          \
        kc4_ = *(const bf16x8*)(kp_ + 2048);                                          \
        kc5_ = *(const bf16x8*)(kp_ + 2080);                                          \
        kc6_ = *(const bf16x8*)(kp_ + 3072);                                          \
        kc7_ = *(const bf16x8*)(kp_ + 3104);                                          \
    }

// softmax over stt (one q-tile's 16 S values/lane), online update, ps write
#define SMPART(mi_, li_, o_, pswX)                                                   \
    {                                                                                 \
        float x0_ = fmaxf(fmaxf(stt[0][0], stt[0][1]), stt[0][2]);                    \
        float x1_ = fmaxf(fmaxf(stt[0][3], stt[1][0]), stt[1][1]);                    \
        float x2_ = fmaxf(fmaxf(stt[1][2], stt[1][3]), stt[2][0]);                    \
        float x3_ = fmaxf(fmaxf(stt[2][1], stt[2][2]), stt[2][3]);                    \
        float x4_ = fmaxf(fmaxf(stt[3][0], stt[3][1]), stt[3][2]);                    \
        float mx_ = fmaxf(fmaxf(fmaxf(x0_, x1_), x2_),                                \
                          fmaxf(fmaxf(x3_, x4_), stt[3][3]));                         \
        mx_ = fmaxf(mx_, __shfl_xor(mx_, 16, 64));                                    \
        mx_ = fmaxf(mx_, __shfl_xor(mx_, 32, 64));                                    \
        const bool nd_ = !__all(mx_ - mi_ <= 8.0f);                                   \
        const float mn_ = nd_ ? fmaxf(mi_, mx_) : mi_;                                \
        float rs_ = 0.f;                                                              \
        _Pragma("unroll") for (int mt_ = 0; mt_ < 4; mt_++)                           \
            _Pragma("unroll") for (int rr_ = 0; rr_ < 4; rr_++) {                     \
                float pv_ = __builtin_amdgcn_exp2f(stt[mt_][rr_] - mn_);              \
                stt[mt_][rr_] = pv_;                                                  \
                rs_ += pv_;                                                           \
            }                                                                         \
        rs_ += __shfl_xor(rs_, 16, 64);                                               \
        rs_ += __shfl_xor(rs_, 32, 64);                                               \
        if (nd_) {                                                                    \
            const float aa_ = __builtin_amdgcn_exp2f(mi_ - mn_);                      \
            mi_ = mn_;                                                                \
            li_ *= aa_;                                                               \
            _Pragma("unroll") for (int mt_ = 0; mt_ < 4; mt_++)                       \
                _Pragma("unroll") for (int rr_ = 0; rr_ < 4; rr_++) o_[mt_][rr_] *= aa_; \
        }                                                                             \
        li_ += rs_;                                                                   \
        _Pragma("unroll") for (int mt_ = 0; mt_ < 4; mt_++) {                         \
            bf16x4 pk_;                                                               \
            pk_[0] = (bf16)stt[mt_][0]; pk_[1] = (bf16)stt[mt_][1];                   \
            pk_[2] = (bf16)stt[mt_][2]; pk_[3] = (bf16)stt[mt_][3];                   \
            *(bf16x4*)((pswX) + l15 * KP2 + mt_ * 16 + quad * 4) = pk_;               \
        }                                                                             \
    }

// one KV slot: V-early, QK from preloaded kc regs, K-prefetch after QK-b
#define KV_STEP2(jtv, nxt, isdiag, T0a_, T0b_, qa0_, qa1_, qb0_, qb1_,                \
                 m_a, l_a, o_a, m_b, l_b, o_b)                                        \
    {                                                                                 \
        const bf16* vp_ = vbase + (size_t)(jtv) * 64;                                 \
        bf16x8 v0_ = *(const bf16x8*)(vp_);                                           \
        bf16x8 v1_ = *(const bf16x8*)(vp_ + 32);                                      \
        bf16x8 v2_ = *(const bf16x8*)(vp_ + 32768);                                   \
        bf16x8 v3_ = *(const bf16x8*)(vp_ + 32768 + 32);                              \
        bf16x8 v4_ = *(const bf16x8*)(vp_ + 65536);                                   \
        bf16x8 v5_ = *(const bf16x8*)(vp_ + 65536 + 32);                              \
        bf16x8 v6_ = *(const bf16x8*)(vp_ + 98304);                                   \
        bf16x8 v7_ = *(const bf16x8*)(vp_ + 98304 + 32);                              \
        floatx4 stt[4];                                                               \
        __builtin_amdgcn_s_setprio(1);                                                \
        { floatx4 z_ = {}; z_ = MFMA16(kc0_, qa0_, z_); z_ = MFMA16(kc1_, qa1_, z_); stt[0] = z_; } \
        { floatx4 z_ = {}; z_ = MFMA16(kc2_, qa0_, z_); z_ = MFMA16(kc3_, qa1_, z_); stt[1] = z_; } \
        { floatx4 z_ = {}; z_ = MFMA16(kc4_, qa0_, z_); z_ = MFMA16(kc5_, qa1_, z_); stt[2] = z_; } \
        { floatx4 z_ = {}; z_ = MFMA16(kc6_, qa0_, z_); z_ = MFMA16(kc7_, qa1_, z_); stt[3] = z_; } \
        __builtin_amdgcn_s_setprio(0);                                                \
        if (isdiag) {                                                                 \
            _Pragma("unroll") for (int mt_ = 0; mt_ < 4; mt_++)                       \
                _Pragma("unroll") for (int rr_ = 0; rr_ < 4; rr_++) {                 \
                    int kv_ = (jtv) * 64 + mt_ * 16 + quad * 4 + rr_;                 \
                    if (kv_ > (T0a_) + l15) stt[mt_][rr_] = -1e30f;                   \
                }                                                                     \
        }                                                                             \
        SMPART(m_a, l_a, o_a, pswa);                                                  \
        __builtin_amdgcn_s_setprio(1);                                                \
        { floatx4 z_ = {}; z_ = MFMA16(kc0_, qb0_, z_); z_ = MFMA16(kc1_, qb1_, z_); stt[0] = z_; } \
        { floatx4 z_ = {}; z_ = MFMA16(kc2_, qb0_, z_); z_ = MFMA16(kc3_, qb1_, z_); stt[1] = z_; } \
        { floatx4 z_ = {}; z_ = MFMA16(kc4_, qb0_, z_); z_ = MFMA16(kc5_, qb1_, z_); stt[2] = z_; } \
        { floatx4 z_ = {}; z_ = MFMA16(kc6_, qb0_, z_); z_ = MFMA16(kc7_, qb1_, z_); stt[3] = z_; } \
        __builtin_amdgcn_s_setprio(0);                                                \
        if ((nxt) >= 0) LOADK(nxt);      /* depth-1 K prefetch (kc dead here) */      \
        if (isdiag) {                                                                 \
            _Pragma("unroll") for (int mt_ = 0; mt_ < 4; mt_++)                       \
                _Pragma("unroll") for (int rr_ = 0; rr_ < 4; rr_++) {                 \
                    int kv_ = (jtv) * 64 + mt_ * 16 + quad * 4 + rr_;                 \
                    if (kv_ > (T0b_) + l15) stt[mt_][rr_] = -1e30f;                   \
                }                                                                     \
        }                                                                             \
        SMPART(m_b, l_b, o_b, pswb);                                                  \
        bf16x8 pa0_ = *(const bf16x8*)(pswa + l15 * KP2 + quad * 8);                  \
        bf16x8 pa1_ = *(const bf16x8*)(pswa + l15 * KP2 + 32 + quad * 8);             \
        bf16x8 pb0_ = *(const bf16x8*)(pswb + l15 * KP2 + quad * 8);                  \
        bf16x8 pb1_ = *(const bf16x8*)(pswb + l15 * KP2 + 32 + quad * 8);             \
        __builtin_amdgcn_s_setprio(1);                                                \
        o_a[0] = MFMA16(v0_, pa0_, o_a[0]);  o_a[0] = MFMA16(v1_, pa1_, o_a[0]);      \
        o_b[0] = MFMA16(v0_, pb0_, o_b[0]);  o_b[0] = MFMA16(v1_, pb1_, o_b[0]);      \
        o_a[1] = MFMA16(v2_, pa0_, o_a[1]);  o_a[1] = MFMA16(v3_, pa1_, o_a[1]);      \
        o_b[1] = MFMA16(v2_, pb0_, o_b[1]);  o_b[1] = MFMA16(v3_, pb1_, o_b[1]);      \
        o_a[2] = MFMA16(v4_, pa0_, o_a[2]);  o_a[2] = MFMA16(v5_, pa1_, o_a[2]);      \
        o_b[2] = MFMA16(v4_, pb0_, o_b[2]);  o_b[2] = MFMA16(v5_, pb1_, o_b[2]);      \
        o_a[3] = MFMA16(v6_, pa0_, o_a[3]);  o_a[3] = MFMA16(v7_, pa1_, o_a[3]);      \
        o_b[3] = MFMA16(v6_, pb0_, o_b[3]);  o_b[3] = MFMA16(v7_, pb1_, o_b[3]);      \
        __builtin_amdgcn_s_setprio(0);                                                \
    }

    // ---- near-pair slots: s in [u0, min(u1, NN)), jt = s
    {
        const int e = (u1 < NN) ? u1 : NN;
        if (u0 < e) {
            bf16x8 qa0 = *(const bf16x8*)qn0;
            bf16x8 qa1 = *(const bf16x8*)(qn0 + 32);
            bf16x8 qb0 = *(const bf16x8*)qn1;
            bf16x8 qb1 = *(const bf16x8*)(qn1 + 32);
            bf16x8 kc0_, kc1_, kc2_, kc3_, kc4_, kc5_, kc6_, kc7_;
            LOADK(u0);
            for (int s = u0; s < e; s++) {
                const int nxt = (s + 1 < e) ? s + 1 : -1;
                KV_STEP2(s, nxt, (s == NN - 1), Tn0, Tn1, qa0, qa1, qb0, qb1,
                         mm0, ll0, o0, mm1, ll1, o1);
            }
        }
    }
    // ---- far-pair slots: s in [max(u0, NN), u1), jt = s - NN
    {
        const int sB = (u0 > NN) ? u0 : NN;
        if (sB < u1) {
            bf16x8 qa0 = *(const bf16x8*)qx0;
            bf16x8 qa1 = *(const bf16x8*)(qx0 + 32);
            bf16x8 qb0 = *(const bf16x8*)qx1;
            bf16x8 qb1 = *(const bf16x8*)(qx1 + 32);
            bf16x8 kc0_, kc1_, kc2_, kc3_, kc4_, kc5_, kc6_, kc7_;
            LOADK(sB - NN);
            for (int s = sB; s < u1; s++) {
                const int nxt = (s + 1 < u1) ? s + 1 - NN : -1;
                KV_STEP2(s - NN, nxt, (s == L - 1), Tf0, Tf1, qa0, qa1, qb0, qb1,
                         mm2, ll2, o2, mm3, ll3, o3);
            }
        }
    }

    // ---- merge: 4 rounds over the quad's tiles (Os unions with ps)
    #pragma unroll
    for (int r = 0; r < 4; r++) {
        __syncthreads();
        float mi = (r == 0) ? mm0 : (r == 1) ? mm1 : (r == 2) ? mm2 : mm3;
        float li = (r == 0) ? ll0 : (r == 1) ? ll1 : (r == 2) ? ll2 : ll3;
        if (lane < 16) { Ms[w][lane] = mi; Ls[w][lane] = li; }
        #pragma unroll
        for (int mt = 0; mt < 4; mt++) {
            floatx4 ov = (r == 0) ? o0[mt] : (r == 1) ? o1[mt] : (r == 2) ? o2[mt] : o3[mt];
            *(floatx4*)(Os + (w * 16 + l15) * OH + mt * 16 + quad * 4) = ov;
        }
        __syncthreads();
        {
            int qq = tid >> 5;               // 0..15
            int h2 = (tid & 31) * 2;         // 0..62
            float Mg = -1e30f;
            #pragma unroll
            for (int u = 0; u < 8; u++) Mg = fmaxf(Mg, Ms[u][qq]);
            float Lg = 0.f, v0 = 0.f, v1 = 0.f;
            #pragma unroll
            for (int u = 0; u < 8; u++) {
                float sw = __builtin_amdgcn_exp2f(Ms[u][qq] - Mg);
                Lg += sw * Ls[u][qq];
                const float* Or = Os + (u * 16 + qq) * OH + h2;
                v0 += sw * Or[0];
                v1 += sw * Or[1];
            }
            float inv = 1.0f / Lg;
            int T0v = (r == 0) ? Tn0 : (r == 1) ? Tn1 : (r == 2) ? Tf0 : Tf1;
            float* op = out + (size_t)(b * 2048 + T0v + qq) * 64 + h2;
            op[0] = v0 * inv;
            op[1] = v1 * inv;
        }
    }
#undef KV_STEP2
#undef SMPART
#undef LOADK
}

// ---------------------------------------------------------------------------
extern "C" void kernel_launch(void* const* d_in, const int* in_sizes, int n_in,
                              void* d_out, int out_size, void* d_ws, size_t ws_size,
                              hipStream_t stream) {
    const float* x  = (const float*)d_in[0];
    const float* Wq = (const float*)d_in[1];
    const float* Wk = (const float*)d_in[2];
    const float* Wv = (const float*)d_in[3];
    float* out = (float*)d_out;

    char* ws = (char*)d_ws;
    bf16* wTf = (bf16*)ws;                              // 393216 B + 4 KB slack
    bf16* q   = (bf16*)(ws + 397312);                   // 2 MB
    bf16* k   = (bf16*)(ws + 397312 + 2097152);
    bf16* vT  = (bf16*)(ws + 397312 + 2 * 2097152);     // [b*64+h][2048]

    hipLaunchKernelGGL(prep_w,   dim3(768), dim3(256), 0, stream, Wq, Wk, Wv, wTf);
    hipLaunchKernelGGL(proj_qkv, dim3(512), dim3(256), 0, stream, x, wTf, q, k, vT);
    hipLaunchKernelGGL(flash,    dim3(256), dim3(512), 0, stream, q, k, vT, out);
}